// Round 1
// baseline (2721.972 us; speedup 1.0000x reference)
//
#include <hip/hip_runtime.h>

#define NN 100000
#define NE 320000
#define DIM 256

// ---------------- degree accumulation ----------------
__global__ void k_degree(const int* __restrict__ src, const int* __restrict__ dst,
                         float* __restrict__ dout, float* __restrict__ din) {
    int e = blockIdx.x * 256 + threadIdx.x;
    if (e < NE) {
        atomicAdd(&dout[src[e]], 1.0f);
        atomicAdd(&din[dst[e]], 1.0f);
    }
}

// ---------------- deg -> rsqrt(max(deg,1)) in place ----------------
__global__ void k_norm(float* __restrict__ dout, float* __restrict__ din) {
    int i = blockIdx.x * 256 + threadIdx.x;
    if (i < NN) {
        dout[i] = rsqrtf(fmaxf(dout[i], 1.0f));
        din[i]  = rsqrtf(fmaxf(din[i],  1.0f));
    }
}

// ---------------- edge-parallel SpMM: agg[dst] += feat[src] * nrm[src] --------
// one wave (64 lanes) per edge, float4 per lane => full 1KiB row per wave
__global__ __launch_bounds__(256)
void k_spmm(const int* __restrict__ src, const int* __restrict__ dst,
            const float* __restrict__ feat, const float* __restrict__ nrm,
            float* __restrict__ agg) {
    int t = threadIdx.x;
    int e = blockIdx.x * 4 + (t >> 6);
    if (e >= NE) return;
    int c = (t & 63) << 2;
    int s = src[e], d = dst[e];
    float w = nrm[s];
    const float4 v = *reinterpret_cast<const float4*>(feat + (size_t)s * DIM + c);
    float* o = agg + (size_t)d * DIM + c;
    atomicAdd(o + 0, v.x * w);
    atomicAdd(o + 1, v.y * w);
    atomicAdd(o + 2, v.z * w);
    atomicAdd(o + 3, v.w * w);
}

// ---------------- fused GEMM: out = relu(nin[i] * (A[i] @ W) + bias) ----------
// BM=128, BN=128, BK=16, 256 threads, 8x8 micro-tile.
// As stored transposed [BK][BM+4] (pad kills write conflicts; reads are b128,
// conflict-free). B columns split tx*4 and 64+tx*4 (2-way = free).
#define BM 128
#define BN 128
#define BK 16

__global__ __launch_bounds__(256)
void k_gemm(const float* __restrict__ A, const float* __restrict__ W,
            const float* __restrict__ bias, const float* __restrict__ nin,
            float* __restrict__ out) {
    __shared__ float As[BK][BM + 4];
    __shared__ float Bs[BK][BN];

    const int t  = threadIdx.x;
    const int tx = t & 15;   // 0..15 -> column groups
    const int ty = t >> 4;   // 0..15 -> row groups
    const int bm = blockIdx.y * BM;
    const int bn = blockIdx.x * BN;

    float acc[8][8] = {};

    for (int k0 = 0; k0 < DIM; k0 += BK) {
        // --- stage A tile (128 rows x 16 k) : 512 float4, 2 per thread ---
        #pragma unroll
        for (int j = 0; j < 2; ++j) {
            int f  = t + 256 * j;
            int r  = f >> 2;       // 0..127
            int c4 = f & 3;        // 0..3  (k-chunk of 4)
            int grow = bm + r;
            float4 v = make_float4(0.f, 0.f, 0.f, 0.f);
            if (grow < NN)
                v = *reinterpret_cast<const float4*>(A + (size_t)grow * DIM + k0 + c4 * 4);
            // transpose into As[k][row]
            As[c4 * 4 + 0][r] = v.x;
            As[c4 * 4 + 1][r] = v.y;
            As[c4 * 4 + 2][r] = v.z;
            As[c4 * 4 + 3][r] = v.w;
        }
        // --- stage B tile (16 k x 128 cols) : 512 float4, 2 per thread ---
        #pragma unroll
        for (int j = 0; j < 2; ++j) {
            int f  = t + 256 * j;
            int r  = f >> 5;       // 0..15
            int c4 = f & 31;       // 0..31
            float4 v = *reinterpret_cast<const float4*>(W + (size_t)(k0 + r) * DIM + bn + c4 * 4);
            *reinterpret_cast<float4*>(&Bs[r][c4 * 4]) = v;
        }
        __syncthreads();

        #pragma unroll
        for (int k = 0; k < BK; ++k) {
            float4 a0 = *reinterpret_cast<const float4*>(&As[k][ty * 8]);
            float4 a1 = *reinterpret_cast<const float4*>(&As[k][ty * 8 + 4]);
            float4 b0 = *reinterpret_cast<const float4*>(&Bs[k][tx * 4]);
            float4 b1 = *reinterpret_cast<const float4*>(&Bs[k][64 + tx * 4]);
            float a[8] = {a0.x, a0.y, a0.z, a0.w, a1.x, a1.y, a1.z, a1.w};
            float b[8] = {b0.x, b0.y, b0.z, b0.w, b1.x, b1.y, b1.z, b1.w};
            #pragma unroll
            for (int r = 0; r < 8; ++r)
                #pragma unroll
                for (int c = 0; c < 8; ++c)
                    acc[r][c] += a[r] * b[c];
        }
        __syncthreads();
    }

    // --- epilogue: scale by nin (dst norm commutes past matmul), +bias, relu ---
    #pragma unroll
    for (int r = 0; r < 8; ++r) {
        int grow = bm + ty * 8 + r;
        if (grow >= NN) break;
        float s = nin[grow];
        float4 o0, o1;
        o0.x = fmaxf(acc[r][0] * s + bias[bn + tx * 4 + 0], 0.f);
        o0.y = fmaxf(acc[r][1] * s + bias[bn + tx * 4 + 1], 0.f);
        o0.z = fmaxf(acc[r][2] * s + bias[bn + tx * 4 + 2], 0.f);
        o0.w = fmaxf(acc[r][3] * s + bias[bn + tx * 4 + 3], 0.f);
        o1.x = fmaxf(acc[r][4] * s + bias[bn + 64 + tx * 4 + 0], 0.f);
        o1.y = fmaxf(acc[r][5] * s + bias[bn + 64 + tx * 4 + 1], 0.f);
        o1.z = fmaxf(acc[r][6] * s + bias[bn + 64 + tx * 4 + 2], 0.f);
        o1.w = fmaxf(acc[r][7] * s + bias[bn + 64 + tx * 4 + 3], 0.f);
        *reinterpret_cast<float4*>(out + (size_t)grow * DIM + bn + tx * 4)      = o0;
        *reinterpret_cast<float4*>(out + (size_t)grow * DIM + bn + 64 + tx * 4) = o1;
    }
}

extern "C" void kernel_launch(void* const* d_in, const int* in_sizes, int n_in,
                              void* d_out, int out_size, void* d_ws, size_t ws_size,
                              hipStream_t stream) {
    const int*   src  = (const int*)d_in[0];
    const int*   dst  = (const int*)d_in[1];
    const float* feat = (const float*)d_in[2];
    const float* W1   = (const float*)d_in[3];
    const float* b1   = (const float*)d_in[4];
    const float* W2   = (const float*)d_in[5];
    const float* b2   = (const float*)d_in[6];
    float* out = (float*)d_out;

    // workspace layout: [norm_out NN][norm_in NN][agg NN*DIM]  (~103.2 MB)
    float* nout = (float*)d_ws;
    float* nin  = nout + NN;
    float* agg  = nin + NN;

    // zero degree accumulators + agg buffer (ws is poisoned 0xAA each call)
    hipMemsetAsync(d_ws, 0, (size_t)(2 * NN + (size_t)NN * DIM) * sizeof(float), stream);

    k_degree<<<(NE + 255) / 256, 256, 0, stream>>>(src, dst, nout, nin);
    k_norm<<<(NN + 255) / 256, 256, 0, stream>>>(nout, nin);

    dim3 ggrid(BN == 128 ? 2 : DIM / BN, (NN + BM - 1) / BM);

    // layer 1: agg = segsum(feat[src]*nout[src]); out = relu(nin*(agg@W1)+b1)
    k_spmm<<<NE / 4, 256, 0, stream>>>(src, dst, feat, nout, agg);
    k_gemm<<<ggrid, 256, 0, stream>>>(agg, W1, b1, nin, out);

    // layer 2: re-zero agg, aggregate h1 (living in d_out), GEMM back into d_out
    hipMemsetAsync(agg, 0, (size_t)NN * DIM * sizeof(float), stream);
    k_spmm<<<NE / 4, 256, 0, stream>>>(src, dst, out, nout, agg);
    k_gemm<<<ggrid, 256, 0, stream>>>(agg, W2, b2, nin, out);
}

// Round 2
// 876.594 us; speedup vs baseline: 3.1052x; 3.1052x over previous
//
#include <hip/hip_runtime.h>

#define NN 100000
#define NE 320000
#define DIM 256

// ---------------- degree histogram (int) ----------------
__global__ void k_degree(const int* __restrict__ src, const int* __restrict__ dst,
                         int* __restrict__ cnt_out, int* __restrict__ cnt_in) {
    int e = blockIdx.x * 256 + threadIdx.x;
    if (e < NE) {
        atomicAdd(&cnt_out[src[e]], 1);
        atomicAdd(&cnt_in[dst[e]], 1);
    }
}

// ---------------- norms: rsqrt(max(deg,1)) ----------------
__global__ void k_norm(const int* __restrict__ cnt_out, const int* __restrict__ cnt_in,
                       float* __restrict__ nout, float* __restrict__ nin) {
    int i = blockIdx.x * 256 + threadIdx.x;
    if (i < NN) {
        nout[i] = rsqrtf(fmaxf((float)cnt_out[i], 1.0f));
        nin[i]  = rsqrtf(fmaxf((float)cnt_in[i],  1.0f));
    }
}

// ---------------- exclusive scan of cnt_in -> base[0..NN] (single block) -----
__global__ __launch_bounds__(1024)
void k_scan(const int* __restrict__ cnt, int* __restrict__ base) {
    __shared__ int sums[1024];
    const int t  = threadIdx.x;
    const int CH = (NN + 1023) / 1024;           // 98
    int lo = t * CH, hi = min(lo + CH, NN);
    int s = 0;
    for (int i = lo; i < hi; ++i) s += cnt[i];
    sums[t] = s;
    __syncthreads();
    // Hillis-Steele inclusive scan (read-old / sync / write / sync)
    for (int off = 1; off < 1024; off <<= 1) {
        int add = (t >= off) ? sums[t - off] : 0;
        __syncthreads();
        sums[t] += add;
        __syncthreads();
    }
    int run = sums[t] - s;                        // exclusive prefix for chunk
    for (int i = lo; i < hi; ++i) { base[i] = run; run += cnt[i]; }
    if (t == 1023) base[NN] = run;                // total (= NE)
}

// ---------------- scatter edges into CSR by dst ----------------
__global__ void k_scatter(const int* __restrict__ src, const int* __restrict__ dst,
                          const int* __restrict__ base, int* __restrict__ cursor,
                          int* __restrict__ csr_src) {
    int e = blockIdx.x * 256 + threadIdx.x;
    if (e < NE) {
        int d = dst[e];
        int p = base[d] + atomicAdd(&cursor[d], 1);
        csr_src[p] = src[e];
    }
}

// ---------------- dst-parallel gather: agg[d] = sum_e feat[src_e]*nout[src_e] -
// one wave per dst node; 64 lanes x float4 = full 256-float row; no atomics.
__global__ __launch_bounds__(256)
void k_gather(const int* __restrict__ csr_src, const int* __restrict__ base,
              const float* __restrict__ feat, const float* __restrict__ nrm,
              float* __restrict__ agg) {
    int t = threadIdx.x;
    int d = blockIdx.x * 4 + (t >> 6);
    if (d >= NN) return;
    int c = (t & 63) << 2;
    int j0 = base[d], j1 = base[d + 1];
    float4 acc = make_float4(0.f, 0.f, 0.f, 0.f);
    for (int j = j0; j < j1; ++j) {
        int s = csr_src[j];
        float w = nrm[s];
        const float4 v = *reinterpret_cast<const float4*>(feat + (size_t)s * DIM + c);
        acc.x += v.x * w; acc.y += v.y * w; acc.z += v.z * w; acc.w += v.w * w;
    }
    *reinterpret_cast<float4*>(agg + (size_t)d * DIM + c) = acc;
}

// ---------------- fused GEMM: out = relu(nin[i] * (A[i] @ W) + bias) ----------
#define BM 128
#define BN 128
#define BK 16

__global__ __launch_bounds__(256)
void k_gemm(const float* __restrict__ A, const float* __restrict__ W,
            const float* __restrict__ bias, const float* __restrict__ nin,
            float* __restrict__ out) {
    __shared__ float As[BK][BM + 4];
    __shared__ float Bs[BK][BN];

    const int t  = threadIdx.x;
    const int tx = t & 15;
    const int ty = t >> 4;
    const int bm = blockIdx.y * BM;
    const int bn = blockIdx.x * BN;

    float acc[8][8] = {};

    for (int k0 = 0; k0 < DIM; k0 += BK) {
        #pragma unroll
        for (int j = 0; j < 2; ++j) {
            int f  = t + 256 * j;
            int r  = f >> 2;
            int c4 = f & 3;
            int grow = bm + r;
            float4 v = make_float4(0.f, 0.f, 0.f, 0.f);
            if (grow < NN)
                v = *reinterpret_cast<const float4*>(A + (size_t)grow * DIM + k0 + c4 * 4);
            As[c4 * 4 + 0][r] = v.x;
            As[c4 * 4 + 1][r] = v.y;
            As[c4 * 4 + 2][r] = v.z;
            As[c4 * 4 + 3][r] = v.w;
        }
        #pragma unroll
        for (int j = 0; j < 2; ++j) {
            int f  = t + 256 * j;
            int r  = f >> 5;
            int c4 = f & 31;
            float4 v = *reinterpret_cast<const float4*>(W + (size_t)(k0 + r) * DIM + bn + c4 * 4);
            *reinterpret_cast<float4*>(&Bs[r][c4 * 4]) = v;
        }
        __syncthreads();

        #pragma unroll
        for (int k = 0; k < BK; ++k) {
            float4 a0 = *reinterpret_cast<const float4*>(&As[k][ty * 8]);
            float4 a1 = *reinterpret_cast<const float4*>(&As[k][ty * 8 + 4]);
            float4 b0 = *reinterpret_cast<const float4*>(&Bs[k][tx * 4]);
            float4 b1 = *reinterpret_cast<const float4*>(&Bs[k][64 + tx * 4]);
            float a[8] = {a0.x, a0.y, a0.z, a0.w, a1.x, a1.y, a1.z, a1.w};
            float b[8] = {b0.x, b0.y, b0.z, b0.w, b1.x, b1.y, b1.z, b1.w};
            #pragma unroll
            for (int r = 0; r < 8; ++r)
                #pragma unroll
                for (int c = 0; c < 8; ++c)
                    acc[r][c] += a[r] * b[c];
        }
        __syncthreads();
    }

    #pragma unroll
    for (int r = 0; r < 8; ++r) {
        int grow = bm + ty * 8 + r;
        if (grow >= NN) break;
        float s = nin[grow];
        float4 o0, o1;
        o0.x = fmaxf(acc[r][0] * s + bias[bn + tx * 4 + 0], 0.f);
        o0.y = fmaxf(acc[r][1] * s + bias[bn + tx * 4 + 1], 0.f);
        o0.z = fmaxf(acc[r][2] * s + bias[bn + tx * 4 + 2], 0.f);
        o0.w = fmaxf(acc[r][3] * s + bias[bn + tx * 4 + 3], 0.f);
        o1.x = fmaxf(acc[r][4] * s + bias[bn + 64 + tx * 4 + 0], 0.f);
        o1.y = fmaxf(acc[r][5] * s + bias[bn + 64 + tx * 4 + 1], 0.f);
        o1.z = fmaxf(acc[r][6] * s + bias[bn + 64 + tx * 4 + 2], 0.f);
        o1.w = fmaxf(acc[r][7] * s + bias[bn + 64 + tx * 4 + 3], 0.f);
        *reinterpret_cast<float4*>(out + (size_t)grow * DIM + bn + tx * 4)      = o0;
        *reinterpret_cast<float4*>(out + (size_t)grow * DIM + bn + 64 + tx * 4) = o1;
    }
}

extern "C" void kernel_launch(void* const* d_in, const int* in_sizes, int n_in,
                              void* d_out, int out_size, void* d_ws, size_t ws_size,
                              hipStream_t stream) {
    const int*   src  = (const int*)d_in[0];
    const int*   dst  = (const int*)d_in[1];
    const float* feat = (const float*)d_in[2];
    const float* W1   = (const float*)d_in[3];
    const float* b1   = (const float*)d_in[4];
    const float* W2   = (const float*)d_in[5];
    const float* b2   = (const float*)d_in[6];
    float* out = (float*)d_out;

    // ws layout (elements): [cnt_out NN][cnt_in NN][cursor NN][base NN+4]
    //                       [nout NN][nin NN][csr_src NE][agg NN*DIM]
    int*   cnt_out = (int*)d_ws;
    int*   cnt_in  = cnt_out + NN;
    int*   cursor  = cnt_in + NN;
    int*   base    = cursor + NN;
    float* nout    = (float*)(base + NN + 4);
    float* nin     = nout + NN;
    int*   csr_src = (int*)(nin + NN);
    float* agg     = (float*)(csr_src + NE);

    // zero the three counter arrays only (everything else is fully written)
    hipMemsetAsync(d_ws, 0, (size_t)3 * NN * sizeof(int), stream);

    k_degree <<<(NE + 255) / 256, 256, 0, stream>>>(src, dst, cnt_out, cnt_in);
    k_norm   <<<(NN + 255) / 256, 256, 0, stream>>>(cnt_out, cnt_in, nout, nin);
    k_scan   <<<1, 1024, 0, stream>>>(cnt_in, base);
    k_scatter<<<(NE + 255) / 256, 256, 0, stream>>>(src, dst, base, cursor, csr_src);

    dim3 ggrid(DIM / BN, (NN + BM - 1) / BM);

    // layer 1
    k_gather<<<(NN + 3) / 4, 256, 0, stream>>>(csr_src, base, feat, nout, agg);
    k_gemm  <<<ggrid, 256, 0, stream>>>(agg, W1, b1, nin, out);

    // layer 2 (h1 lives in d_out; gather reads it, GEMM overwrites it)
    k_gather<<<(NN + 3) / 4, 256, 0, stream>>>(csr_src, base, out, nout, agg);
    k_gemm  <<<ggrid, 256, 0, stream>>>(agg, W2, b2, nin, out);
}

// Round 3
// 574.198 us; speedup vs baseline: 4.7405x; 1.5266x over previous
//
#include <hip/hip_runtime.h>

#define NN 100000
#define NE 320000
#define DIM 256

typedef _Float16 half8 __attribute__((ext_vector_type(8)));
typedef _Float16 half4 __attribute__((ext_vector_type(4)));
typedef float float4v __attribute__((ext_vector_type(4)));

// ---------------- degree histogram (int) ----------------
__global__ void k_degree(const int* __restrict__ src, const int* __restrict__ dst,
                         int* __restrict__ cnt_out, int* __restrict__ cnt_in) {
    int e = blockIdx.x * 256 + threadIdx.x;
    if (e < NE) {
        atomicAdd(&cnt_out[src[e]], 1);
        atomicAdd(&cnt_in[dst[e]], 1);
    }
}

// ---------------- norms: rsqrt(max(deg,1)) ----------------
__global__ void k_norm(const int* __restrict__ cnt_out, const int* __restrict__ cnt_in,
                       float* __restrict__ nout, float* __restrict__ nin) {
    int i = blockIdx.x * 256 + threadIdx.x;
    if (i < NN) {
        nout[i] = rsqrtf(fmaxf((float)cnt_out[i], 1.0f));
        nin[i]  = rsqrtf(fmaxf((float)cnt_in[i],  1.0f));
    }
}

// ---------------- exclusive scan of cnt_in -> base[0..NN] (single block) -----
__global__ __launch_bounds__(1024)
void k_scan(const int* __restrict__ cnt, int* __restrict__ base) {
    __shared__ int sums[1024];
    const int t  = threadIdx.x;
    const int CH = (NN + 1023) / 1024;
    int lo = t * CH, hi = min(lo + CH, NN);
    int s = 0;
    for (int i = lo; i < hi; ++i) s += cnt[i];
    sums[t] = s;
    __syncthreads();
    for (int off = 1; off < 1024; off <<= 1) {
        int add = (t >= off) ? sums[t - off] : 0;
        __syncthreads();
        sums[t] += add;
        __syncthreads();
    }
    int run = sums[t] - s;
    for (int i = lo; i < hi; ++i) { base[i] = run; run += cnt[i]; }
    if (t == 1023) base[NN] = run;
}

// ---------------- scatter edges into CSR by dst ----------------
__global__ void k_scatter(const int* __restrict__ src, const int* __restrict__ dst,
                          const int* __restrict__ base, int* __restrict__ cursor,
                          int* __restrict__ csr_src) {
    int e = blockIdx.x * 256 + threadIdx.x;
    if (e < NE) {
        int d = dst[e];
        int p = base[d] + atomicAdd(&cursor[d], 1);
        csr_src[p] = src[e];
    }
}

// ---------------- weight prep: WT[n][k] = (f16) W[k][n], both layers ---------
__global__ void k_prepw(const float* __restrict__ W1, const float* __restrict__ W2,
                        _Float16* __restrict__ WT1, _Float16* __restrict__ WT2) {
    int i = blockIdx.x * 256 + threadIdx.x;   // 0 .. 65535
    int k = i >> 8, n = i & 255;
    WT1[(size_t)n * DIM + k] = (_Float16)W1[(size_t)k * DIM + n];
    WT2[(size_t)n * DIM + k] = (_Float16)W2[(size_t)k * DIM + n];
}

// ---------------- dst-parallel gather, fp16 output ----------------
// one wave per dst node; 64 lanes x 4 elems = full 256 row; fp32 accumulate.
template <typename InT>
__global__ __launch_bounds__(256)
void k_gather(const int* __restrict__ csr_src, const int* __restrict__ base,
              const InT* __restrict__ feat, const float* __restrict__ nrm,
              _Float16* __restrict__ agg) {
    int t = threadIdx.x;
    int d = blockIdx.x * 4 + (t >> 6);
    if (d >= NN) return;
    int c = (t & 63) << 2;
    int j0 = base[d], j1 = base[d + 1];
    float ax = 0.f, ay = 0.f, az = 0.f, aw = 0.f;
    for (int j = j0; j < j1; ++j) {
        int s = csr_src[j];
        float w = nrm[s];
        const InT* p = feat + (size_t)s * DIM + c;
        float vx, vy, vz, vw;
        if constexpr (sizeof(InT) == 4) {
            float4 v = *reinterpret_cast<const float4*>(p);
            vx = v.x; vy = v.y; vz = v.z; vw = v.w;
        } else {
            half4 v = *reinterpret_cast<const half4*>(p);
            vx = (float)v[0]; vy = (float)v[1]; vz = (float)v[2]; vw = (float)v[3];
        }
        ax += vx * w; ay += vy * w; az += vz * w; aw += vw * w;
    }
    half4 o; o[0] = (_Float16)ax; o[1] = (_Float16)ay; o[2] = (_Float16)az; o[3] = (_Float16)aw;
    *reinterpret_cast<half4*>(agg + (size_t)d * DIM + c) = o;
}

// ---------------- MFMA GEMM: out = relu(nin[m] * (A[m,:] @ W) + bias) --------
// A: M x 256 fp16 row-major. WT: 256 x 256 fp16 (WT[n][k]). OutT: float or f16.
// 256 thr = 4 waves (2x2); wave computes 64x64 via 4x4 mfma_f32_16x16x32_f16.
#define LDA 40   // 32 + 8 pad halves -> 80 B row stride, conflict-free b128 reads

template <typename OutT>
__global__ __launch_bounds__(256)
void k_gemm(const _Float16* __restrict__ A, const _Float16* __restrict__ WT,
            const float* __restrict__ bias, const float* __restrict__ nin,
            OutT* __restrict__ out) {
    __shared__ _Float16 As[128 * LDA];
    __shared__ _Float16 Bs[128 * LDA];

    const int t    = threadIdx.x;
    const int lane = t & 63;
    const int w    = t >> 6;
    const int wm   = w >> 1, wn = w & 1;
    const int l15  = lane & 15, quad = lane >> 4;
    const int bm   = blockIdx.y * 128;
    const int bn   = blockIdx.x * 128;

    float4v acc[4][4] = {};

    for (int k0 = 0; k0 < DIM; k0 += 32) {
        #pragma unroll
        for (int j = 0; j < 2; ++j) {
            int f = t + 256 * j;          // 0..511
            int r = f >> 2, c = f & 3;    // r: row, c: 8-half chunk
            half8 v = {};
            int grow = bm + r;
            if (grow < NN)
                v = *reinterpret_cast<const half8*>(A + (size_t)grow * DIM + k0 + c * 8);
            *reinterpret_cast<half8*>(&As[r * LDA + c * 8]) = v;
        }
        #pragma unroll
        for (int j = 0; j < 2; ++j) {
            int f = t + 256 * j;
            int r = f >> 2, c = f & 3;
            half8 v = *reinterpret_cast<const half8*>(WT + (size_t)(bn + r) * DIM + k0 + c * 8);
            *reinterpret_cast<half8*>(&Bs[r * LDA + c * 8]) = v;
        }
        __syncthreads();

        half8 af[4], bf[4];
        #pragma unroll
        for (int mt = 0; mt < 4; ++mt)
            af[mt] = *reinterpret_cast<half8*>(&As[(wm * 64 + mt * 16 + l15) * LDA + quad * 8]);
        #pragma unroll
        for (int nt = 0; nt < 4; ++nt)
            bf[nt] = *reinterpret_cast<half8*>(&Bs[(wn * 64 + nt * 16 + l15) * LDA + quad * 8]);

        #pragma unroll
        for (int mt = 0; mt < 4; ++mt)
            #pragma unroll
            for (int nt = 0; nt < 4; ++nt)
                acc[mt][nt] = __builtin_amdgcn_mfma_f32_16x16x32_f16(af[mt], bf[nt], acc[mt][nt], 0, 0, 0);
        __syncthreads();
    }

    // epilogue: C/D layout col = lane&15, row = quad*4 + r
    float bcol[4];
    #pragma unroll
    for (int nt = 0; nt < 4; ++nt)
        bcol[nt] = bias[bn + wn * 64 + nt * 16 + l15];

    #pragma unroll
    for (int mt = 0; mt < 4; ++mt) {
        #pragma unroll
        for (int r = 0; r < 4; ++r) {
            int row = bm + wm * 64 + mt * 16 + quad * 4 + r;
            if (row < NN) {
                float s = nin[row];
                #pragma unroll
                for (int nt = 0; nt < 4; ++nt) {
                    int col = bn + wn * 64 + nt * 16 + l15;
                    float v = fmaxf(acc[mt][nt][r] * s + bcol[nt], 0.f);
                    out[(size_t)row * DIM + col] = (OutT)v;
                }
            }
        }
    }
}

extern "C" void kernel_launch(void* const* d_in, const int* in_sizes, int n_in,
                              void* d_out, int out_size, void* d_ws, size_t ws_size,
                              hipStream_t stream) {
    const int*   src  = (const int*)d_in[0];
    const int*   dst  = (const int*)d_in[1];
    const float* feat = (const float*)d_in[2];
    const float* W1   = (const float*)d_in[3];
    const float* b1   = (const float*)d_in[4];
    const float* W2   = (const float*)d_in[5];
    const float* b2   = (const float*)d_in[6];
    float* out = (float*)d_out;

    // ws layout: [cnt_out NN][cnt_in NN][cursor NN][base NN+4] ints,
    //            [nout NN][nin NN] floats, [csr_src NE] ints,
    //            [WT1 64K][WT2 64K][agg_h NN*DIM] halves         (~56 MB)
    int*      cnt_out = (int*)d_ws;
    int*      cnt_in  = cnt_out + NN;
    int*      cursor  = cnt_in + NN;
    int*      base    = cursor + NN;
    float*    nout    = (float*)(base + NN + 4);
    float*    nin     = nout + NN;
    int*      csr_src = (int*)(nin + NN);
    _Float16* WT1     = (_Float16*)(csr_src + NE);
    _Float16* WT2     = WT1 + DIM * DIM;
    _Float16* agg_h   = WT2 + DIM * DIM;

    // h1 (fp16, relu'd) lives in d_out's storage as scratch; fully
    // overwritten by the final fp32 GEMM-2 store afterwards.
    _Float16* h1_h = (_Float16*)d_out;

    hipMemsetAsync(d_ws, 0, (size_t)3 * NN * sizeof(int), stream);

    k_degree <<<(NE + 255) / 256, 256, 0, stream>>>(src, dst, cnt_out, cnt_in);
    k_norm   <<<(NN + 255) / 256, 256, 0, stream>>>(cnt_out, cnt_in, nout, nin);
    k_scan   <<<1, 1024, 0, stream>>>(cnt_in, base);
    k_scatter<<<(NE + 255) / 256, 256, 0, stream>>>(src, dst, base, cursor, csr_src);
    k_prepw  <<<(DIM * DIM + 255) / 256, 256, 0, stream>>>(W1, W2, WT1, WT2);

    dim3 ggrid(2, (NN + 127) / 128);

    // layer 1: gather fp32 feat -> fp16 agg; GEMM -> fp16 relu'd h1 (in d_out)
    k_gather<float>   <<<(NN + 3) / 4, 256, 0, stream>>>(csr_src, base, feat, nout, agg_h);
    k_gemm<_Float16>  <<<ggrid, 256, 0, stream>>>(agg_h, WT1, b1, nin, h1_h);

    // layer 2: gather fp16 h1 -> fp16 agg; GEMM -> fp32 final out
    k_gather<_Float16><<<(NN + 3) / 4, 256, 0, stream>>>(csr_src, base, h1_h, nout, agg_h);
    k_gemm<float>     <<<ggrid, 256, 0, stream>>>(agg_h, WT2, b2, nin, out);
}

// Round 4
// 424.599 us; speedup vs baseline: 6.4107x; 1.3523x over previous
//
#include <hip/hip_runtime.h>

#define NN 100000
#define NE 320000
#define DIM 256
#define SCAN_NBLK ((NN + 1023) / 1024)   // 98

typedef _Float16 half8 __attribute__((ext_vector_type(8)));
typedef _Float16 half4 __attribute__((ext_vector_type(4)));
typedef float float4v __attribute__((ext_vector_type(4)));

// ---------------- degree histogram (int) ----------------
__global__ void k_degree(const int* __restrict__ src, const int* __restrict__ dst,
                         int* __restrict__ cnt_out, int* __restrict__ cnt_in) {
    int e = blockIdx.x * 256 + threadIdx.x;
    if (e < NE) {
        atomicAdd(&cnt_out[src[e]], 1);
        atomicAdd(&cnt_in[dst[e]], 1);
    }
}

// ---------------- norms: rsqrt(max(deg,1)) ----------------
__global__ void k_norm(const int* __restrict__ cnt_out, const int* __restrict__ cnt_in,
                       float* __restrict__ nout, float* __restrict__ nin) {
    int i = blockIdx.x * 256 + threadIdx.x;
    if (i < NN) {
        nout[i] = rsqrtf(fmaxf((float)cnt_out[i], 1.0f));
        nin[i]  = rsqrtf(fmaxf((float)cnt_in[i],  1.0f));
    }
}

// ---------------- hierarchical exclusive scan of cnt_in -> base -------------
// phase 1: per-block (1024 elems) local exclusive scan + block partial
__global__ __launch_bounds__(256)
void k_scan1(const int* __restrict__ cnt, int* __restrict__ base,
             int* __restrict__ part) {
    __shared__ int sums[256];
    const int t  = threadIdx.x;
    const int i0 = blockIdx.x * 1024 + t * 4;
    int v[4];
    if (i0 + 3 < NN) {
        int4 q = *reinterpret_cast<const int4*>(cnt + i0);
        v[0] = q.x; v[1] = q.y; v[2] = q.z; v[3] = q.w;
    } else {
        #pragma unroll
        for (int j = 0; j < 4; ++j) v[j] = (i0 + j < NN) ? cnt[i0 + j] : 0;
    }
    int s = v[0] + v[1] + v[2] + v[3];
    sums[t] = s;
    __syncthreads();
    for (int off = 1; off < 256; off <<= 1) {
        int a = (t >= off) ? sums[t - off] : 0;
        __syncthreads();
        sums[t] += a;
        __syncthreads();
    }
    int run = sums[t] - s;                      // exclusive prefix of this thread
    #pragma unroll
    for (int j = 0; j < 4; ++j) {
        if (i0 + j < NN) base[i0 + j] = run;
        run += v[j];
    }
    if (t == 255) part[blockIdx.x] = sums[255];
}

// phase 2: exclusive scan of the 98 block partials (single small block)
__global__ __launch_bounds__(128)
void k_scan2(int* __restrict__ part) {
    __shared__ int s[128];
    const int t = threadIdx.x;
    int v = (t < SCAN_NBLK) ? part[t] : 0;
    s[t] = v;
    __syncthreads();
    for (int off = 1; off < 128; off <<= 1) {
        int a = (t >= off) ? s[t - off] : 0;
        __syncthreads();
        s[t] += a;
        __syncthreads();
    }
    if (t < SCAN_NBLK) part[t] = s[t] - v;
}

// phase 3: add block offsets; base[NN] = NE (total is statically known)
__global__ __launch_bounds__(256)
void k_scan3(int* __restrict__ base, const int* __restrict__ part) {
    const int off = part[blockIdx.x];
    const int i0  = blockIdx.x * 1024 + threadIdx.x * 4;
    #pragma unroll
    for (int j = 0; j < 4; ++j)
        if (i0 + j < NN) base[i0 + j] += off;
    if (blockIdx.x == 0 && threadIdx.x == 0) base[NN] = NE;
}

// ---------------- scatter edges into CSR by dst ----------------
__global__ void k_scatter(const int* __restrict__ src, const int* __restrict__ dst,
                          const int* __restrict__ base, int* __restrict__ cursor,
                          int* __restrict__ csr_src) {
    int e = blockIdx.x * 256 + threadIdx.x;
    if (e < NE) {
        int d = dst[e];
        int p = base[d] + atomicAdd(&cursor[d], 1);
        csr_src[p] = src[e];
    }
}

// ---------------- weight prep: WT[n][k] = (f16) W[k][n], both layers ---------
__global__ void k_prepw(const float* __restrict__ W1, const float* __restrict__ W2,
                        _Float16* __restrict__ WT1, _Float16* __restrict__ WT2) {
    int i = blockIdx.x * 256 + threadIdx.x;
    int k = i >> 8, n = i & 255;
    WT1[(size_t)n * DIM + k] = (_Float16)W1[(size_t)k * DIM + n];
    WT2[(size_t)n * DIM + k] = (_Float16)W2[(size_t)k * DIM + n];
}

// ---------------- dst-parallel gather, fp16 output ----------------
template <typename InT>
__global__ __launch_bounds__(256)
void k_gather(const int* __restrict__ csr_src, const int* __restrict__ base,
              const InT* __restrict__ feat, const float* __restrict__ nrm,
              _Float16* __restrict__ agg) {
    int t = threadIdx.x;
    int d = blockIdx.x * 4 + (t >> 6);
    if (d >= NN) return;
    int c = (t & 63) << 2;
    int j0 = base[d], j1 = base[d + 1];
    float ax = 0.f, ay = 0.f, az = 0.f, aw = 0.f;
    for (int j = j0; j < j1; ++j) {
        int s = csr_src[j];
        float w = nrm[s];
        const InT* p = feat + (size_t)s * DIM + c;
        float vx, vy, vz, vw;
        if constexpr (sizeof(InT) == 4) {
            float4 v = *reinterpret_cast<const float4*>(p);
            vx = v.x; vy = v.y; vz = v.z; vw = v.w;
        } else {
            half4 v = *reinterpret_cast<const half4*>(p);
            vx = (float)v[0]; vy = (float)v[1]; vz = (float)v[2]; vw = (float)v[3];
        }
        ax += vx * w; ay += vy * w; az += vz * w; aw += vw * w;
    }
    half4 o; o[0] = (_Float16)ax; o[1] = (_Float16)ay; o[2] = (_Float16)az; o[3] = (_Float16)aw;
    *reinterpret_cast<half4*>(agg + (size_t)d * DIM + c) = o;
}

// ---------------- MFMA GEMM: out = relu(nin[m] * (A[m,:] @ W) + bias) --------
#define LDA 40   // 32 + 8 pad halves -> 80 B row stride, conflict-free b128 reads

template <typename OutT>
__global__ __launch_bounds__(256)
void k_gemm(const _Float16* __restrict__ A, const _Float16* __restrict__ WT,
            const float* __restrict__ bias, const float* __restrict__ nin,
            OutT* __restrict__ out) {
    __shared__ _Float16 As[128 * LDA];
    __shared__ _Float16 Bs[128 * LDA];

    const int t    = threadIdx.x;
    const int lane = t & 63;
    const int w    = t >> 6;
    const int wm   = w >> 1, wn = w & 1;
    const int l15  = lane & 15, quad = lane >> 4;
    const int bm   = blockIdx.y * 128;
    const int bn   = blockIdx.x * 128;

    float4v acc[4][4] = {};

    for (int k0 = 0; k0 < DIM; k0 += 32) {
        #pragma unroll
        for (int j = 0; j < 2; ++j) {
            int f = t + 256 * j;
            int r = f >> 2, c = f & 3;
            half8 v = {};
            int grow = bm + r;
            if (grow < NN)
                v = *reinterpret_cast<const half8*>(A + (size_t)grow * DIM + k0 + c * 8);
            *reinterpret_cast<half8*>(&As[r * LDA + c * 8]) = v;
        }
        #pragma unroll
        for (int j = 0; j < 2; ++j) {
            int f = t + 256 * j;
            int r = f >> 2, c = f & 3;
            half8 v = *reinterpret_cast<const half8*>(WT + (size_t)(bn + r) * DIM + k0 + c * 8);
            *reinterpret_cast<half8*>(&Bs[r * LDA + c * 8]) = v;
        }
        __syncthreads();

        half8 af[4], bf[4];
        #pragma unroll
        for (int mt = 0; mt < 4; ++mt)
            af[mt] = *reinterpret_cast<half8*>(&As[(wm * 64 + mt * 16 + l15) * LDA + quad * 8]);
        #pragma unroll
        for (int nt = 0; nt < 4; ++nt)
            bf[nt] = *reinterpret_cast<half8*>(&Bs[(wn * 64 + nt * 16 + l15) * LDA + quad * 8]);

        #pragma unroll
        for (int mt = 0; mt < 4; ++mt)
            #pragma unroll
            for (int nt = 0; nt < 4; ++nt)
                acc[mt][nt] = __builtin_amdgcn_mfma_f32_16x16x32_f16(af[mt], bf[nt], acc[mt][nt], 0, 0, 0);
        __syncthreads();
    }

    float bcol[4];
    #pragma unroll
    for (int nt = 0; nt < 4; ++nt)
        bcol[nt] = bias[bn + wn * 64 + nt * 16 + l15];

    #pragma unroll
    for (int mt = 0; mt < 4; ++mt) {
        #pragma unroll
        for (int r = 0; r < 4; ++r) {
            int row = bm + wm * 64 + mt * 16 + quad * 4 + r;
            if (row < NN) {
                float s = nin[row];
                #pragma unroll
                for (int nt = 0; nt < 4; ++nt) {
                    int col = bn + wn * 64 + nt * 16 + l15;
                    float v = fmaxf(acc[mt][nt][r] * s + bcol[nt], 0.f);
                    out[(size_t)row * DIM + col] = (OutT)v;
                }
            }
        }
    }
}

extern "C" void kernel_launch(void* const* d_in, const int* in_sizes, int n_in,
                              void* d_out, int out_size, void* d_ws, size_t ws_size,
                              hipStream_t stream) {
    const int*   src  = (const int*)d_in[0];
    const int*   dst  = (const int*)d_in[1];
    const float* feat = (const float*)d_in[2];
    const float* W1   = (const float*)d_in[3];
    const float* b1   = (const float*)d_in[4];
    const float* W2   = (const float*)d_in[5];
    const float* b2   = (const float*)d_in[6];
    float* out = (float*)d_out;

    // ws layout: [cnt_out NN][cnt_in NN][cursor NN][base NN+4][part 128] ints,
    //            [nout NN][nin NN] floats, [csr_src NE] ints,
    //            [WT1 64K][WT2 64K][agg_h NN*DIM] halves
    int*      cnt_out = (int*)d_ws;
    int*      cnt_in  = cnt_out + NN;
    int*      cursor  = cnt_in + NN;
    int*      base    = cursor + NN;
    int*      part    = base + NN + 4;
    float*    nout    = (float*)(part + 128);
    float*    nin     = nout + NN;
    int*      csr_src = (int*)(nin + NN);
    _Float16* WT1     = (_Float16*)(csr_src + NE);
    _Float16* WT2     = WT1 + DIM * DIM;
    _Float16* agg_h   = WT2 + DIM * DIM;

    _Float16* h1_h = (_Float16*)d_out;   // fp16 h1 scratch inside d_out

    hipMemsetAsync(d_ws, 0, (size_t)3 * NN * sizeof(int), stream);

    k_degree <<<(NE + 255) / 256, 256, 0, stream>>>(src, dst, cnt_out, cnt_in);
    k_norm   <<<(NN + 255) / 256, 256, 0, stream>>>(cnt_out, cnt_in, nout, nin);
    k_scan1  <<<SCAN_NBLK, 256, 0, stream>>>(cnt_in, base, part);
    k_scan2  <<<1, 128, 0, stream>>>(part);
    k_scan3  <<<SCAN_NBLK, 256, 0, stream>>>(base, part);
    k_scatter<<<(NE + 255) / 256, 256, 0, stream>>>(src, dst, base, cursor, csr_src);
    k_prepw  <<<(DIM * DIM + 255) / 256, 256, 0, stream>>>(W1, W2, WT1, WT2);

    dim3 ggrid(2, (NN + 127) / 128);

    // layer 1
    k_gather<float>   <<<(NN + 3) / 4, 256, 0, stream>>>(csr_src, base, feat, nout, agg_h);
    k_gemm<_Float16>  <<<ggrid, 256, 0, stream>>>(agg_h, WT1, b1, nin, h1_h);

    // layer 2
    k_gather<_Float16><<<(NN + 3) / 4, 256, 0, stream>>>(csr_src, base, h1_h, nout, agg_h);
    k_gemm<float>     <<<ggrid, 256, 0, stream>>>(agg_h, WT2, b2, nin, out);
}

// Round 5
// 399.591 us; speedup vs baseline: 6.8119x; 1.0626x over previous
//
#include <hip/hip_runtime.h>

#define NN 100000
#define NE 320000
#define DIM 256
#define SCAN_NBLK ((NN + 1023) / 1024)   // 98

typedef _Float16 half8 __attribute__((ext_vector_type(8)));
typedef _Float16 half4 __attribute__((ext_vector_type(4)));
typedef float float4v __attribute__((ext_vector_type(4)));

// ---------------- degree histogram (int) ----------------
__global__ void k_degree(const int* __restrict__ src, const int* __restrict__ dst,
                         int* __restrict__ cnt_out, int* __restrict__ cnt_in) {
    int e = blockIdx.x * 256 + threadIdx.x;
    if (e < NE) {
        atomicAdd(&cnt_out[src[e]], 1);
        atomicAdd(&cnt_in[dst[e]], 1);
    }
}

// ---------------- norms: rsqrt(max(deg,1)) ----------------
__global__ void k_norm(const int* __restrict__ cnt_out, const int* __restrict__ cnt_in,
                       float* __restrict__ nout, float* __restrict__ nin) {
    int i = blockIdx.x * 256 + threadIdx.x;
    if (i < NN) {
        nout[i] = rsqrtf(fmaxf((float)cnt_out[i], 1.0f));
        nin[i]  = rsqrtf(fmaxf((float)cnt_in[i],  1.0f));
    }
}

// ---------------- hierarchical exclusive scan of cnt_in -> base -------------
__global__ __launch_bounds__(256)
void k_scan1(const int* __restrict__ cnt, int* __restrict__ base,
             int* __restrict__ part) {
    __shared__ int sums[256];
    const int t  = threadIdx.x;
    const int i0 = blockIdx.x * 1024 + t * 4;
    int v[4];
    if (i0 + 3 < NN) {
        int4 q = *reinterpret_cast<const int4*>(cnt + i0);
        v[0] = q.x; v[1] = q.y; v[2] = q.z; v[3] = q.w;
    } else {
        #pragma unroll
        for (int j = 0; j < 4; ++j) v[j] = (i0 + j < NN) ? cnt[i0 + j] : 0;
    }
    int s = v[0] + v[1] + v[2] + v[3];
    sums[t] = s;
    __syncthreads();
    for (int off = 1; off < 256; off <<= 1) {
        int a = (t >= off) ? sums[t - off] : 0;
        __syncthreads();
        sums[t] += a;
        __syncthreads();
    }
    int run = sums[t] - s;
    #pragma unroll
    for (int j = 0; j < 4; ++j) {
        if (i0 + j < NN) base[i0 + j] = run;
        run += v[j];
    }
    if (t == 255) part[blockIdx.x] = sums[255];
}

__global__ __launch_bounds__(128)
void k_scan2(int* __restrict__ part) {
    __shared__ int s[128];
    const int t = threadIdx.x;
    int v = (t < SCAN_NBLK) ? part[t] : 0;
    s[t] = v;
    __syncthreads();
    for (int off = 1; off < 128; off <<= 1) {
        int a = (t >= off) ? s[t - off] : 0;
        __syncthreads();
        s[t] += a;
        __syncthreads();
    }
    if (t < SCAN_NBLK) part[t] = s[t] - v;
}

__global__ __launch_bounds__(256)
void k_scan3(int* __restrict__ base, const int* __restrict__ part) {
    const int off = part[blockIdx.x];
    const int i0  = blockIdx.x * 1024 + threadIdx.x * 4;
    #pragma unroll
    for (int j = 0; j < 4; ++j)
        if (i0 + j < NN) base[i0 + j] += off;
    if (blockIdx.x == 0 && threadIdx.x == 0) base[NN] = NE;
}

// ---------------- scatter edges into CSR by dst ----------------
__global__ void k_scatter(const int* __restrict__ src, const int* __restrict__ dst,
                          const int* __restrict__ base, int* __restrict__ cursor,
                          int* __restrict__ csr_src) {
    int e = blockIdx.x * 256 + threadIdx.x;
    if (e < NE) {
        int d = dst[e];
        int p = base[d] + atomicAdd(&cursor[d], 1);
        csr_src[p] = src[e];
    }
}

// ---------------- weight prep: WT[n][k] = (f16) W[k][n], both layers ---------
__global__ void k_prepw(const float* __restrict__ W1, const float* __restrict__ W2,
                        _Float16* __restrict__ WT1, _Float16* __restrict__ WT2) {
    int i = blockIdx.x * 256 + threadIdx.x;
    int k = i >> 8, n = i & 255;
    WT1[(size_t)n * DIM + k] = (_Float16)W1[(size_t)k * DIM + n];
    WT2[(size_t)n * DIM + k] = (_Float16)W2[(size_t)k * DIM + n];
}

// ---------------- feat prep: feat_h = f16(feat * nout[row]) ------------------
__global__ __launch_bounds__(256)
void k_prepf(const float* __restrict__ feat, const float* __restrict__ nout,
             _Float16* __restrict__ fh) {
    int i = blockIdx.x * 256 + threadIdx.x;        // float4-group index
    if (i >= NN * DIM / 4) return;
    int row = i >> 6;
    float w = nout[row];
    float4 v = reinterpret_cast<const float4*>(feat)[i];
    half4 o;
    o[0] = (_Float16)(v.x * w); o[1] = (_Float16)(v.y * w);
    o[2] = (_Float16)(v.z * w); o[3] = (_Float16)(v.w * w);
    reinterpret_cast<half4*>(fh)[i] = o;
}

// ---------------- dst-parallel gather: agg[d] = sum fp16 rows ----------------
// one wave per dst; lane loads its own csr index once, __shfl broadcasts;
// 4-wide manual unroll => 4 independent row loads in flight.
__global__ __launch_bounds__(256)
void k_gather(const int* __restrict__ csr_src, const int* __restrict__ base,
              const _Float16* __restrict__ feat, _Float16* __restrict__ agg) {
    const int t = threadIdx.x, lane = t & 63;
    const int d = blockIdx.x * 4 + (t >> 6);
    if (d >= NN) return;
    const int c  = lane << 2;
    const int j0 = base[d], j1 = base[d + 1];
    const int deg = j1 - j0;
    const int cap = min(deg, 64);
    int myidx = (lane < cap) ? csr_src[j0 + lane] : 0;
    float ax = 0.f, ay = 0.f, az = 0.f, aw = 0.f;
    int e = 0;
    for (; e + 4 <= cap; e += 4) {
        int s0 = __shfl(myidx, e + 0), s1 = __shfl(myidx, e + 1);
        int s2 = __shfl(myidx, e + 2), s3 = __shfl(myidx, e + 3);
        half4 v0 = *reinterpret_cast<const half4*>(feat + (size_t)s0 * DIM + c);
        half4 v1 = *reinterpret_cast<const half4*>(feat + (size_t)s1 * DIM + c);
        half4 v2 = *reinterpret_cast<const half4*>(feat + (size_t)s2 * DIM + c);
        half4 v3 = *reinterpret_cast<const half4*>(feat + (size_t)s3 * DIM + c);
        ax += (float)v0[0] + (float)v1[0] + (float)v2[0] + (float)v3[0];
        ay += (float)v0[1] + (float)v1[1] + (float)v2[1] + (float)v3[1];
        az += (float)v0[2] + (float)v1[2] + (float)v2[2] + (float)v3[2];
        aw += (float)v0[3] + (float)v1[3] + (float)v2[3] + (float)v3[3];
    }
    for (; e < cap; ++e) {
        int s = __shfl(myidx, e);
        half4 v = *reinterpret_cast<const half4*>(feat + (size_t)s * DIM + c);
        ax += (float)v[0]; ay += (float)v[1]; az += (float)v[2]; aw += (float)v[3];
    }
    for (int j = j0 + 64; j < j1; ++j) {           // deg>64 fallback (rare)
        int s = csr_src[j];
        half4 v = *reinterpret_cast<const half4*>(feat + (size_t)s * DIM + c);
        ax += (float)v[0]; ay += (float)v[1]; az += (float)v[2]; aw += (float)v[3];
    }
    half4 o; o[0] = (_Float16)ax; o[1] = (_Float16)ay; o[2] = (_Float16)az; o[3] = (_Float16)aw;
    *reinterpret_cast<half4*>(agg + (size_t)d * DIM + c) = o;
}

// ---------------- MFMA GEMM: out = relu(nin[m]*(A@W)+bias) [*nout if PRESCALE]
#define LDA 40   // 32 + 8 pad halves -> 80 B row stride, conflict-free b128 reads

template <typename OutT, bool PRESCALE>
__global__ __launch_bounds__(256)
void k_gemm(const _Float16* __restrict__ A, const _Float16* __restrict__ WT,
            const float* __restrict__ bias, const float* __restrict__ nin,
            const float* __restrict__ nout, OutT* __restrict__ out) {
    __shared__ _Float16 As[128 * LDA];
    __shared__ _Float16 Bs[128 * LDA];

    const int t    = threadIdx.x;
    const int lane = t & 63;
    const int w    = t >> 6;
    const int wm   = w >> 1, wn = w & 1;
    const int l15  = lane & 15, quad = lane >> 4;
    const int bm   = blockIdx.y * 128;
    const int bn   = blockIdx.x * 128;

    float4v acc[4][4] = {};

    for (int k0 = 0; k0 < DIM; k0 += 32) {
        #pragma unroll
        for (int j = 0; j < 2; ++j) {
            int f = t + 256 * j;
            int r = f >> 2, c = f & 3;
            half8 v = {};
            int grow = bm + r;
            if (grow < NN)
                v = *reinterpret_cast<const half8*>(A + (size_t)grow * DIM + k0 + c * 8);
            *reinterpret_cast<half8*>(&As[r * LDA + c * 8]) = v;
        }
        #pragma unroll
        for (int j = 0; j < 2; ++j) {
            int f = t + 256 * j;
            int r = f >> 2, c = f & 3;
            half8 v = *reinterpret_cast<const half8*>(WT + (size_t)(bn + r) * DIM + k0 + c * 8);
            *reinterpret_cast<half8*>(&Bs[r * LDA + c * 8]) = v;
        }
        __syncthreads();

        half8 af[4], bf[4];
        #pragma unroll
        for (int mt = 0; mt < 4; ++mt)
            af[mt] = *reinterpret_cast<half8*>(&As[(wm * 64 + mt * 16 + l15) * LDA + quad * 8]);
        #pragma unroll
        for (int nt = 0; nt < 4; ++nt)
            bf[nt] = *reinterpret_cast<half8*>(&Bs[(wn * 64 + nt * 16 + l15) * LDA + quad * 8]);

        #pragma unroll
        for (int mt = 0; mt < 4; ++mt)
            #pragma unroll
            for (int nt = 0; nt < 4; ++nt)
                acc[mt][nt] = __builtin_amdgcn_mfma_f32_16x16x32_f16(af[mt], bf[nt], acc[mt][nt], 0, 0, 0);
        __syncthreads();
    }

    float bcol[4];
    #pragma unroll
    for (int nt = 0; nt < 4; ++nt)
        bcol[nt] = bias[bn + wn * 64 + nt * 16 + l15];

    #pragma unroll
    for (int mt = 0; mt < 4; ++mt) {
        #pragma unroll
        for (int r = 0; r < 4; ++r) {
            int row = bm + wm * 64 + mt * 16 + quad * 4 + r;
            if (row < NN) {
                float s = nin[row];
                float ps = PRESCALE ? nout[row] : 1.0f;
                #pragma unroll
                for (int nt = 0; nt < 4; ++nt) {
                    int col = bn + wn * 64 + nt * 16 + l15;
                    float v = fmaxf(acc[mt][nt][r] * s + bcol[nt], 0.f) * ps;
                    out[(size_t)row * DIM + col] = (OutT)v;
                }
            }
        }
    }
}

extern "C" void kernel_launch(void* const* d_in, const int* in_sizes, int n_in,
                              void* d_out, int out_size, void* d_ws, size_t ws_size,
                              hipStream_t stream) {
    const int*   src  = (const int*)d_in[0];
    const int*   dst  = (const int*)d_in[1];
    const float* feat = (const float*)d_in[2];
    const float* W1   = (const float*)d_in[3];
    const float* b1   = (const float*)d_in[4];
    const float* W2   = (const float*)d_in[5];
    const float* b2   = (const float*)d_in[6];
    float* out = (float*)d_out;

    // ws layout: [cnt_out NN][cnt_in NN][cursor NN][base NN+4][part 128] ints,
    //            [nout NN][nin NN] floats, [csr_src NE] ints,
    //            [WT1 64K][WT2 64K][fh NN*DIM] halves   (~55 MB)
    int*      cnt_out = (int*)d_ws;
    int*      cnt_in  = cnt_out + NN;
    int*      cursor  = cnt_in + NN;
    int*      base    = cursor + NN;
    int*      part    = base + NN + 4;
    float*    nout    = (float*)(part + 128);
    float*    nin     = nout + NN;
    int*      csr_src = (int*)(nin + NN);
    _Float16* WT1     = (_Float16*)(csr_src + NE);
    _Float16* WT2     = WT1 + DIM * DIM;
    _Float16* fh      = WT2 + DIM * DIM;     // feat_h for layer 1; agg2 for layer 2

    // d_out (102.4 MB fp32) doubles as fp16 scratch:
    //   lower half = agg1, upper half = h1 (pre-scaled by nout, relu'd)
    _Float16* agg1 = (_Float16*)d_out;
    _Float16* h1   = agg1 + (size_t)NN * DIM;
    _Float16* agg2 = fh;                      // reuse fh region after gather-1

    hipMemsetAsync(d_ws, 0, (size_t)3 * NN * sizeof(int), stream);

    k_degree <<<(NE + 255) / 256, 256, 0, stream>>>(src, dst, cnt_out, cnt_in);
    k_norm   <<<(NN + 255) / 256, 256, 0, stream>>>(cnt_out, cnt_in, nout, nin);
    k_scan1  <<<SCAN_NBLK, 256, 0, stream>>>(cnt_in, base, part);
    k_scan2  <<<1, 128, 0, stream>>>(part);
    k_scan3  <<<SCAN_NBLK, 256, 0, stream>>>(base, part);
    k_scatter<<<(NE + 255) / 256, 256, 0, stream>>>(src, dst, base, cursor, csr_src);
    k_prepw  <<<(DIM * DIM + 255) / 256, 256, 0, stream>>>(W1, W2, WT1, WT2);
    k_prepf  <<<(NN * DIM / 4 + 255) / 256, 256, 0, stream>>>(feat, nout, fh);

    dim3 ggrid(2, (NN + 127) / 128);

    // layer 1: gather fh -> agg1 (d_out lo); GEMM -> h1 (d_out hi, f16, *nout)
    k_gather<<<(NN + 3) / 4, 256, 0, stream>>>(csr_src, base, fh, agg1);
    k_gemm<_Float16, true><<<ggrid, 256, 0, stream>>>(agg1, WT1, b1, nin, nout, h1);

    // layer 2: gather h1 -> agg2 (ws, fh region); GEMM -> final fp32 out
    k_gather<<<(NN + 3) / 4, 256, 0, stream>>>(csr_src, base, h1, agg2);
    k_gemm<float, false><<<ggrid, 256, 0, stream>>>(agg2, WT2, b2, nin, nout, out);
}

// Round 6
// 396.705 us; speedup vs baseline: 6.8614x; 1.0073x over previous
//
#include <hip/hip_runtime.h>

#define NN 100000
#define NE 320000
#define DIM 256
#define SCAN_NBLK ((NN + 1023) / 1024)   // 98
#define FEAT_BLKS (NN * DIM / 4 / 256)   // 25000 float4-groups blocks

typedef _Float16 half8 __attribute__((ext_vector_type(8)));
typedef _Float16 half4 __attribute__((ext_vector_type(4)));
typedef float float4v __attribute__((ext_vector_type(4)));

// ---------------- degree histogram (int) ----------------
__global__ void k_degree(const int* __restrict__ src, const int* __restrict__ dst,
                         int* __restrict__ cnt_out, int* __restrict__ cnt_in) {
    int e = blockIdx.x * 256 + threadIdx.x;
    if (e < NE) {
        atomicAdd(&cnt_out[src[e]], 1);
        atomicAdd(&cnt_in[dst[e]], 1);
    }
}

// ------- scan phase 1 (+ fused norm computation: nout/nin from degrees) ------
__global__ __launch_bounds__(256)
void k_scan1(const int* __restrict__ cnt_in, const int* __restrict__ cnt_out,
             int* __restrict__ base, int* __restrict__ part,
             float* __restrict__ nout, float* __restrict__ nin) {
    __shared__ int sums[256];
    const int t  = threadIdx.x;
    const int i0 = blockIdx.x * 1024 + t * 4;
    int v[4];
    if (i0 + 3 < NN) {
        int4 q = *reinterpret_cast<const int4*>(cnt_in + i0);
        v[0] = q.x; v[1] = q.y; v[2] = q.z; v[3] = q.w;
        int4 qo = *reinterpret_cast<const int4*>(cnt_out + i0);
        float4 no, ni;
        no.x = rsqrtf(fmaxf((float)qo.x, 1.f)); no.y = rsqrtf(fmaxf((float)qo.y, 1.f));
        no.z = rsqrtf(fmaxf((float)qo.z, 1.f)); no.w = rsqrtf(fmaxf((float)qo.w, 1.f));
        ni.x = rsqrtf(fmaxf((float)v[0], 1.f)); ni.y = rsqrtf(fmaxf((float)v[1], 1.f));
        ni.z = rsqrtf(fmaxf((float)v[2], 1.f)); ni.w = rsqrtf(fmaxf((float)v[3], 1.f));
        *reinterpret_cast<float4*>(nout + i0) = no;
        *reinterpret_cast<float4*>(nin  + i0) = ni;
    } else {
        #pragma unroll
        for (int j = 0; j < 4; ++j) {
            int i = i0 + j;
            v[j] = (i < NN) ? cnt_in[i] : 0;
            if (i < NN) {
                nout[i] = rsqrtf(fmaxf((float)cnt_out[i], 1.f));
                nin[i]  = rsqrtf(fmaxf((float)v[j], 1.f));
            }
        }
    }
    int s = v[0] + v[1] + v[2] + v[3];
    sums[t] = s;
    __syncthreads();
    for (int off = 1; off < 256; off <<= 1) {
        int a = (t >= off) ? sums[t - off] : 0;
        __syncthreads();
        sums[t] += a;
        __syncthreads();
    }
    int run = sums[t] - s;
    #pragma unroll
    for (int j = 0; j < 4; ++j) {
        if (i0 + j < NN) base[i0 + j] = run;
        run += v[j];
    }
    if (t == 255) part[blockIdx.x] = sums[255];
}

__global__ __launch_bounds__(128)
void k_scan2(int* __restrict__ part) {
    __shared__ int s[128];
    const int t = threadIdx.x;
    int v = (t < SCAN_NBLK) ? part[t] : 0;
    s[t] = v;
    __syncthreads();
    for (int off = 1; off < 128; off <<= 1) {
        int a = (t >= off) ? s[t - off] : 0;
        __syncthreads();
        s[t] += a;
        __syncthreads();
    }
    if (t < SCAN_NBLK) part[t] = s[t] - v;
}

__global__ __launch_bounds__(256)
void k_scan3(int* __restrict__ base, const int* __restrict__ part) {
    const int off = part[blockIdx.x];
    const int i0  = blockIdx.x * 1024 + threadIdx.x * 4;
    #pragma unroll
    for (int j = 0; j < 4; ++j)
        if (i0 + j < NN) base[i0 + j] += off;
    if (blockIdx.x == 0 && threadIdx.x == 0) base[NN] = NE;
}

// ---------------- scatter edges into CSR by dst ----------------
__global__ void k_scatter(const int* __restrict__ src, const int* __restrict__ dst,
                          const int* __restrict__ base, int* __restrict__ cursor,
                          int* __restrict__ csr_src) {
    int e = blockIdx.x * 256 + threadIdx.x;
    if (e < NE) {
        int d = dst[e];
        int p = base[d] + atomicAdd(&cursor[d], 1);
        csr_src[p] = src[e];
    }
}

// -------- merged prep: blocks [0,FEAT_BLKS) do feat_h = f16(feat*nout);
//          blocks [FEAT_BLKS, FEAT_BLKS+256) do WT1/WT2 f16 transpose --------
__global__ __launch_bounds__(256)
void k_prep(const float* __restrict__ feat, const float* __restrict__ nout,
            _Float16* __restrict__ fh,
            const float* __restrict__ W1, const float* __restrict__ W2,
            _Float16* __restrict__ WT1, _Float16* __restrict__ WT2) {
    int b = blockIdx.x;
    if (b < FEAT_BLKS) {
        int i = b * 256 + threadIdx.x;            // float4-group index
        int row = i >> 6;
        float w = nout[row];
        float4 v = reinterpret_cast<const float4*>(feat)[i];
        half4 o;
        o[0] = (_Float16)(v.x * w); o[1] = (_Float16)(v.y * w);
        o[2] = (_Float16)(v.z * w); o[3] = (_Float16)(v.w * w);
        reinterpret_cast<half4*>(fh)[i] = o;
    } else {
        int i = (b - FEAT_BLKS) * 256 + threadIdx.x;   // 0..65535
        int k = i >> 8, n = i & 255;
        WT1[(size_t)n * DIM + k] = (_Float16)W1[(size_t)k * DIM + n];
        WT2[(size_t)n * DIM + k] = (_Float16)W2[(size_t)k * DIM + n];
    }
}

// ---------------- dst-parallel gather: agg[d] = sum fp16 rows ----------------
// one wave per dst node. Wave splits into two 32-lane halves; half h handles
// edges h, h+2, h+4, ... (same node => cap is wave-uniform, no divergence).
// Each lane loads half8 (16B); 32 lanes cover the 512B row. Degree-class
// uniform branches issue all loads of a node as straight-line code.
__global__ __launch_bounds__(256)
void k_gather(const int* __restrict__ csr_src, const int* __restrict__ base,
              const _Float16* __restrict__ feat, _Float16* __restrict__ agg) {
    const int t = threadIdx.x, lane = t & 63;
    const int half = lane >> 5, sl = lane & 31;
    const int d = blockIdx.x * 4 + (t >> 6);
    if (d >= NN) return;
    const int c  = sl << 3;                       // 8 halves per lane
    const int j0 = base[d], j1 = base[d + 1];
    const int deg = j1 - j0;
    const int cap = min(deg, 64);
    int myidx = (lane < cap) ? csr_src[j0 + lane] : 0;
    float acc[8] = {};

#define GATHER_ROUND(E0)                                                      \
    {                                                                         \
        bool pa = (E0) + half < cap, pb = (E0) + 2 + half < cap;              \
        int  sa = __shfl(myidx, (E0) + half);                                 \
        int  sb = __shfl(myidx, (E0) + 2 + half);                             \
        half8 va = {}, vb = {};                                               \
        if (pa) va = *reinterpret_cast<const half8*>(feat + (size_t)sa * DIM + c); \
        if (pb) vb = *reinterpret_cast<const half8*>(feat + (size_t)sb * DIM + c); \
        _Pragma("unroll")                                                     \
        for (int q = 0; q < 8; ++q) acc[q] += (float)va[q] + (float)vb[q];    \
    }

    if (cap > 0)  GATHER_ROUND(0)      // edges 0..3
    if (cap > 4)  GATHER_ROUND(4)      // edges 4..7
    if (cap > 8)  GATHER_ROUND(8)      // edges 8..11
    if (cap > 12) GATHER_ROUND(12)     // edges 12..15
    for (int e = 16 + half; e < cap; e += 2) {          // deg 17..64 (rare)
        int s = __shfl(myidx, e);
        half8 v = *reinterpret_cast<const half8*>(feat + (size_t)s * DIM + c);
        #pragma unroll
        for (int q = 0; q < 8; ++q) acc[q] += (float)v[q];
    }
    for (int j = j0 + 64 + half; j < j1; j += 2) {      // deg > 64 (ultra rare)
        int s = csr_src[j];
        half8 v = *reinterpret_cast<const half8*>(feat + (size_t)s * DIM + c);
        #pragma unroll
        for (int q = 0; q < 8; ++q) acc[q] += (float)v[q];
    }
#undef GATHER_ROUND

    #pragma unroll
    for (int q = 0; q < 8; ++q) acc[q] += __shfl_xor(acc[q], 32);
    if (half == 0) {
        half8 o;
        #pragma unroll
        for (int q = 0; q < 8; ++q) o[q] = (_Float16)acc[q];
        *reinterpret_cast<half8*>(agg + (size_t)d * DIM + c) = o;
    }
}

// ---------------- MFMA GEMM: out = relu(nin[m]*(A@W)+bias) [*nout if PRESCALE]
#define LDA 40   // 32 + 8 pad halves -> 80 B row stride, conflict-free b128 reads

template <typename OutT, bool PRESCALE>
__global__ __launch_bounds__(256)
void k_gemm(const _Float16* __restrict__ A, const _Float16* __restrict__ WT,
            const float* __restrict__ bias, const float* __restrict__ nin,
            const float* __restrict__ nout, OutT* __restrict__ out) {
    __shared__ _Float16 As[128 * LDA];
    __shared__ _Float16 Bs[128 * LDA];

    const int t    = threadIdx.x;
    const int lane = t & 63;
    const int w    = t >> 6;
    const int wm   = w >> 1, wn = w & 1;
    const int l15  = lane & 15, quad = lane >> 4;
    const int bm   = blockIdx.y * 128;
    const int bn   = blockIdx.x * 128;

    float4v acc[4][4] = {};

    for (int k0 = 0; k0 < DIM; k0 += 32) {
        #pragma unroll
        for (int j = 0; j < 2; ++j) {
            int f = t + 256 * j;
            int r = f >> 2, c = f & 3;
            half8 v = {};
            int grow = bm + r;
            if (grow < NN)
                v = *reinterpret_cast<const half8*>(A + (size_t)grow * DIM + k0 + c * 8);
            *reinterpret_cast<half8*>(&As[r * LDA + c * 8]) = v;
        }
        #pragma unroll
        for (int j = 0; j < 2; ++j) {
            int f = t + 256 * j;
            int r = f >> 2, c = f & 3;
            half8 v = *reinterpret_cast<const half8*>(WT + (size_t)(bn + r) * DIM + k0 + c * 8);
            *reinterpret_cast<half8*>(&Bs[r * LDA + c * 8]) = v;
        }
        __syncthreads();

        half8 af[4], bf[4];
        #pragma unroll
        for (int mt = 0; mt < 4; ++mt)
            af[mt] = *reinterpret_cast<half8*>(&As[(wm * 64 + mt * 16 + l15) * LDA + quad * 8]);
        #pragma unroll
        for (int nt = 0; nt < 4; ++nt)
            bf[nt] = *reinterpret_cast<half8*>(&Bs[(wn * 64 + nt * 16 + l15) * LDA + quad * 8]);

        #pragma unroll
        for (int mt = 0; mt < 4; ++mt)
            #pragma unroll
            for (int nt = 0; nt < 4; ++nt)
                acc[mt][nt] = __builtin_amdgcn_mfma_f32_16x16x32_f16(af[mt], bf[nt], acc[mt][nt], 0, 0, 0);
        __syncthreads();
    }

    float bcol[4];
    #pragma unroll
    for (int nt = 0; nt < 4; ++nt)
        bcol[nt] = bias[bn + wn * 64 + nt * 16 + l15];

    #pragma unroll
    for (int mt = 0; mt < 4; ++mt) {
        #pragma unroll
        for (int r = 0; r < 4; ++r) {
            int row = bm + wm * 64 + mt * 16 + quad * 4 + r;
            if (row < NN) {
                float s = nin[row];
                float ps = PRESCALE ? nout[row] : 1.0f;
                #pragma unroll
                for (int nt = 0; nt < 4; ++nt) {
                    int col = bn + wn * 64 + nt * 16 + l15;
                    float v = fmaxf(acc[mt][nt][r] * s + bcol[nt], 0.f) * ps;
                    out[(size_t)row * DIM + col] = (OutT)v;
                }
            }
        }
    }
}

extern "C" void kernel_launch(void* const* d_in, const int* in_sizes, int n_in,
                              void* d_out, int out_size, void* d_ws, size_t ws_size,
                              hipStream_t stream) {
    const int*   src  = (const int*)d_in[0];
    const int*   dst  = (const int*)d_in[1];
    const float* feat = (const float*)d_in[2];
    const float* W1   = (const float*)d_in[3];
    const float* b1   = (const float*)d_in[4];
    const float* W2   = (const float*)d_in[5];
    const float* b2   = (const float*)d_in[6];
    float* out = (float*)d_out;

    // ws layout: [cnt_out NN][cnt_in NN][cursor NN][base NN+4][part 128] ints,
    //            [nout NN][nin NN] floats, [csr_src NE] ints,
    //            [WT1 64K][WT2 64K][fh NN*DIM] halves   (~55 MB)
    int*      cnt_out = (int*)d_ws;
    int*      cnt_in  = cnt_out + NN;
    int*      cursor  = cnt_in + NN;
    int*      base    = cursor + NN;
    int*      part    = base + NN + 4;
    float*    nout    = (float*)(part + 128);
    float*    nin     = nout + NN;
    int*      csr_src = (int*)(nin + NN);
    _Float16* WT1     = (_Float16*)(csr_src + NE);
    _Float16* WT2     = WT1 + DIM * DIM;
    _Float16* fh      = WT2 + DIM * DIM;     // feat_h for layer 1; agg2 for layer 2

    // d_out (102.4 MB fp32) doubles as fp16 scratch:
    //   lower half = agg1, upper half = h1 (pre-scaled by nout, relu'd)
    _Float16* agg1 = (_Float16*)d_out;
    _Float16* h1   = agg1 + (size_t)NN * DIM;
    _Float16* agg2 = fh;                      // reuse fh region after gather-1

    hipMemsetAsync(d_ws, 0, (size_t)3 * NN * sizeof(int), stream);

    k_degree <<<(NE + 255) / 256, 256, 0, stream>>>(src, dst, cnt_out, cnt_in);
    k_scan1  <<<SCAN_NBLK, 256, 0, stream>>>(cnt_in, cnt_out, base, part, nout, nin);
    k_scan2  <<<1, 128, 0, stream>>>(part);
    k_scan3  <<<SCAN_NBLK, 256, 0, stream>>>(base, part);
    k_scatter<<<(NE + 255) / 256, 256, 0, stream>>>(src, dst, base, cursor, csr_src);
    k_prep   <<<FEAT_BLKS + 256, 256, 0, stream>>>(feat, nout, fh, W1, W2, WT1, WT2);

    dim3 ggrid(2, (NN + 127) / 128);

    // layer 1: gather fh -> agg1 (d_out lo); GEMM -> h1 (d_out hi, f16, *nout)
    k_gather<<<(NN + 3) / 4, 256, 0, stream>>>(csr_src, base, fh, agg1);
    k_gemm<_Float16, true><<<ggrid, 256, 0, stream>>>(agg1, WT1, b1, nin, nout, h1);

    // layer 2: gather h1 -> agg2 (ws, fh region); GEMM -> final fp32 out
    k_gather<<<(NN + 3) / 4, 256, 0, stream>>>(csr_src, base, h1, agg2);
    k_gemm<float, false><<<ggrid, 256, 0, stream>>>(agg2, WT2, b2, nin, nout, out);
}